// Round 7
// baseline (161.004 us; speedup 1.0000x reference)
//
#include <hip/hip_runtime.h>
#include <stdint.h>

#define BS 8
#define HH 192
#define WW 192
#define HW (HH*WW)     /* 36864 */
#define KK 16
#define QCAP 256       /* u32 entries per (wave,query) queue */
#define DRAIN_THR 192  /* site adds <=64 entries -> max 255 < QCAP */
#define PAD 1e-4f      /* covers fma-filter vs exact-rn error (~2e-6) */

typedef unsigned long long u64;

// ---------- helpers ----------

__device__ __forceinline__ uint32_t fkey(float f) {
    uint32_t u = __float_as_uint(f);
    uint32_t mask = (uint32_t)((int32_t)u >> 31) | 0x80000000u;
    return u ^ mask;
}
__device__ __forceinline__ float inv_fkey(uint32_t v) {
    uint32_t u = (v & 0x80000000u) ? (v ^ 0x80000000u) : ~v;
    return __uint_as_float(u);
}

__device__ __forceinline__ u64 umin64(u64 a, u64 b) { return a < b ? a : b; }

__device__ __forceinline__ u64 wave_min_u64(u64 v) {
    #pragma unroll
    for (int off = 32; off >= 1; off >>= 1) {
        uint32_t lo = (uint32_t)v, hi = (uint32_t)(v >> 32);
        lo = __shfl_xor(lo, off, 64);
        hi = __shfl_xor(hi, off, 64);
        u64 o = ((u64)hi << 32) | lo;
        v = umin64(v, o);
    }
    return v;
}

__device__ __forceinline__ void insert64(u64 (&kept)[KK], u64 key) {
    #pragma unroll
    for (int j = KK - 1; j >= 1; --j) {
        u64 a = kept[j - 1];
        u64 mn = umin64(kept[j], key);
        kept[j] = (key < a) ? a : mn;
    }
    kept[0] = umin64(kept[0], key);
}

__device__ __forceinline__ uint32_t lanerank(u64 pm) {
    return __builtin_amdgcn_mbcnt_hi((uint32_t)(pm >> 32),
             __builtin_amdgcn_mbcnt_lo((uint32_t)pm, 0));
}

// binary search in monotone key space: smallest hi with wave-count(khi<=hi) >= 16.
// Sound when initial hi satisfies count(hi) >= 16.
__device__ __forceinline__ uint32_t refine_core(uint32_t (&khi)[KK], uint32_t hi, int iters) {
    uint32_t lo = 0x00800000u;             // fkey(-FLT_MAX)
    #pragma unroll 1
    for (int t = 0; t < iters; ++t) {
        uint32_t mid = lo + ((hi - lo) >> 1);
        int c = 0;
        #pragma unroll
        for (int j = 0; j < KK; ++j) c += (khi[j] <= mid) ? 1 : 0;
        #pragma unroll
        for (int off = 32; off >= 1; off >>= 1) c += __shfl_xor(c, off, 64);
        if (c >= KK) hi = mid; else lo = mid + 1;
    }
    return hi;
}

__device__ __forceinline__ uint32_t refine_k(const u64 (&kept)[KK], uint32_t hi, int iters) {
    uint32_t kh[KK];
    #pragma unroll
    for (int j = 0; j < KK; ++j) kh[j] = (uint32_t)(kept[j] >> 32);
    return refine_core(kh, hi, iters);
}

__device__ __forceinline__ float exact_rsq(float a, float b, float c) {
    return __fadd_rn(__fadd_rn(__fmul_rn(a, a), __fmul_rn(b, b)), __fmul_rn(c, c));
}
__device__ __forceinline__ float exact_sim(float c0, float c1, float c2, float rsq, float4 pq) {
    float cr = __fadd_rn(__fadd_rn(__fmul_rn(c0, pq.x), __fmul_rn(c1, pq.y)), __fmul_rn(c2, pq.z));
    return __fadd_rn(__fsub_rn(rsq, __fmul_rn(2.0f, cr)), pq.w);
}

// drain queue entries (idx4<<4 | nibble): gather pixels, exact keys, insert
__device__ __forceinline__ void drain_q(const uint32_t* qw, uint32_t scnt,
                                        u64 (&kept)[KK], const float* __restrict__ imgb,
                                        float4 pq, int lane) {
    for (uint32_t e = (uint32_t)lane; e < scnt; e += 64) {
        uint32_t ent = qw[e];
        uint32_t p0i = (ent >> 4) * 4;
        uint32_t nib = ent & 15u;
        #pragma unroll
        for (int bit = 0; bit < 4; ++bit) {
            if (nib & (1u << bit)) {
                uint32_t p = p0i + bit;
                float c0 = imgb[p], c1 = imgb[p + HW], c2 = imgb[p + 2 * HW];
                float rs = exact_rsq(c0, c1, c2);
                float s  = exact_sim(c0, c1, c2, rs, pq);
                insert64(kept, ((u64)fkey(s) << 32) | p);
            }
        }
    }
}

__device__ __forceinline__ int stage_compact(const u64 (&kept)[KK], uint32_t tk, u64* cb, int lane) {
    int c = 0;
    #pragma unroll
    for (int j = 0; j < KK; ++j) c += ((uint32_t)(kept[j] >> 32) <= tk) ? 1 : 0;
    int pref = c;
    #pragma unroll
    for (int i = 1; i < 64; i <<= 1) {
        int t = __shfl_up(pref, i, 64);
        if (lane >= i) pref += t;
    }
    int M = __shfl(pref, 63, 64);
    int base = pref - c;
    if (M <= 64) {
        #pragma unroll
        for (int j = 0; j < KK; ++j)
            if (j < c) cb[base + j] = kept[j];     // kept sorted: prefix = entries <= tk
    }
    return M;
}

__device__ __forceinline__ void select16(u64 (&kept)[KK], int M, const u64* cb, u64* mrow, int lane) {
    if (M <= 64) {
        u64 my = (lane < M) ? cb[lane] : ~0ull;
        int rank = 0;
        #pragma unroll 1
        for (int m = 0; m < M; ++m) rank += (cb[m] < my) ? 1 : 0;
        if (lane < M && rank < KK) mrow[rank] = my;
    } else {   // exact fallback
        #pragma unroll 1
        for (int r = 0; r < KK; ++r) {
            u64 m = wave_min_u64(kept[0]);
            if (kept[0] == m) {
                #pragma unroll
                for (int j = 0; j < KK - 1; ++j) kept[j] = kept[j + 1];
                kept[KK - 1] = ~0ull;
            }
            if (lane == 0) mrow[r] = m;
        }
    }
}

// ---------- kernel 1: block = 2 queries of image b; 4 waves split image, both queries ----------
__global__ __launch_bounds__(256) void topk_kernel(const float* __restrict__ pred,
                                                   const float* __restrict__ ref,
                                                   float* __restrict__ partial) {
    __shared__ uint32_t qbuf[4][2][QCAP];   // 8 KB
    __shared__ u64 cbufs[4][64];            // 2 KB (wave-private, reused q0 then q1)
    __shared__ u64 mbuf[2][64];             // 1 KB
    __shared__ float4 spool[2];

    int lane = threadIdx.x & 63;
    int wid  = threadIdx.x >> 6;
    int b  = blockIdx.x & 7;                // XCD swizzle: image -> one XCD's L2
    int qp = blockIdx.x >> 3;               // 0..127

    // ---- pooled for the 2 queries (threads 0,1) ----
    if (threadIdx.x < 2) {
        int l = qp * 2 + threadIdx.x;
        int i = l * BS + b;                 // scrambled flat grid row
        int b2 = i >> 8, l2 = i & 255;
        const float* pr = pred + ((b2 * 256 + l2) * 8);
        float x = pr[0], y = pr[1];
        float fx = rintf(__fsub_rn(__fmul_rn(x, 192.0f), 0.5f));
        float fy = rintf(__fsub_rn(__fmul_rn(y, 192.0f), 0.5f));
        int ix = (int)fx, iy = (int)fy;
        int inb = (ix >= 0 && ix < WW && iy >= 0 && iy < HH) ? 1 : 0;
        int ixc = min(max(ix, 0), WW - 1);
        int iyc = min(max(iy, 0), HH - 1);
        float m = (float)inb;
        const float* img = ref + b * 3 * HW + iyc * WW + ixc;
        float p0 = __fmul_rn(img[0], m);
        float p1 = __fmul_rn(img[HW], m);
        float p2 = __fmul_rn(img[2 * HW], m);
        float psq = __fadd_rn(__fadd_rn(__fmul_rn(p0, p0), __fmul_rn(p1, p1)), __fmul_rn(p2, p2));
        spool[threadIdx.x] = make_float4(p0, p1, p2, psq);
    }
    __syncthreads();
    float4 pq0 = spool[0];
    float4 pq1 = spool[1];

    const float*  imgb = ref + (size_t)b * 3 * HW;
    const float4* p0g  = (const float4*)imgb;
    int wq4 = wid * 2304;                   // wave's quarter (float4 units)
    uint32_t* qw0 = qbuf[wid][0];
    uint32_t* qw1 = qbuf[wid][1];

    // ---- warm-up: sites 0..3, approx sims (floats) for tau search ----
    float ws0[KK], ws1[KK];
    #pragma unroll
    for (int it = 0; it < 4; ++it) {
        int v = wq4 + it * 64 + lane;
        float4 a0 = p0g[v], a1 = p0g[v + 9216], a2 = p0g[v + 18432];
        #define WARM(comp, e)                                                              \
        {                                                                                  \
            float rsf = fmaf(a2.comp, a2.comp, fmaf(a1.comp, a1.comp, a0.comp*a0.comp));   \
            float cr0 = fmaf(a2.comp, pq0.z, fmaf(a1.comp, pq0.y, a0.comp*pq0.x));         \
            float cr1 = fmaf(a2.comp, pq1.z, fmaf(a1.comp, pq1.y, a0.comp*pq1.x));         \
            ws0[it * 4 + e] = fmaf(-2.0f, cr0, rsf) + pq0.w;                               \
            ws1[it * 4 + e] = fmaf(-2.0f, cr1, rsf) + pq1.w;                               \
        }
        WARM(x, 0) WARM(y, 1) WARM(z, 2) WARM(w, 3)
        #undef WARM
    }
    uint32_t tk0, tk1;
    {
        uint32_t kh[KK];
        #pragma unroll
        for (int j = 0; j < KK; ++j) kh[j] = fkey(ws0[j]);
        tk0 = refine_core(kh, 0xFF7FFFFFu, 12);
        #pragma unroll
        for (int j = 0; j < KK; ++j) kh[j] = fkey(ws1[j]);
        tk1 = refine_core(kh, 0xFF7FFFFFu, 12);
    }
    float tauf0 = inv_fkey(tk0) + PAD;      // padded pass threshold (float domain)
    float tauf1 = inv_fkey(tk1) + PAD;
    uint32_t brk0 = fkey(tauf0 + PAD);      // sound bracket for first exact refine
    uint32_t brk1 = fkey(tauf1 + PAD);
    float h0 = (pq0.w - tauf0) * 0.5f;      // filter offset: pass <=> cr >= rsf*0.5 + h
    float h1 = (pq1.w - tauf1) * 0.5f;

    u64 kept0[KK], kept1[KK];
    #pragma unroll
    for (int j = 0; j < KK; ++j) { kept0[j] = ~0ull; kept1[j] = ~0ull; }
    uint32_t scnt0 = 0, scnt1 = 0;
    bool first0 = true, first1 = true;

    #define PUSHN(nib, qw, scnt)                                                \
    {                                                                           \
        u64 pm = __ballot((nib) != 0);                                          \
        if (pm) {                                                               \
            if (nib) {                                                          \
                uint32_t rnk = lanerank(pm);                                    \
                (qw)[(scnt) + rnk] = (v << 4) | (nib);                          \
            }                                                                   \
            (scnt) += (uint32_t)__popcll(pm);                                   \
        }                                                                       \
    }

    #define MAYBE_DRAIN(N, THR)                                                 \
    if (scnt##N >= (THR)) {                                                     \
        drain_q(qw##N, scnt##N, kept##N, imgb, pq##N, lane);                    \
        scnt##N = 0;                                                            \
        tk##N = refine_k(kept##N, first##N ? brk##N : tk##N, first##N ? 12 : 8);\
        first##N = false;                                                       \
        tauf##N = inv_fkey(tk##N) + PAD;                                        \
        h##N = (pq##N.w - tauf##N) * 0.5f;                                      \
    }

    // ---- warm survivors -> queues (count >= 16 per query guaranteed) ----
    #pragma unroll
    for (int it = 0; it < 4; ++it) {
        uint32_t v = (uint32_t)(wq4 + it * 64 + lane);
        uint32_t nib0 = (ws0[it*4+0] <= tauf0 ? 1u : 0u) | (ws0[it*4+1] <= tauf0 ? 2u : 0u)
                      | (ws0[it*4+2] <= tauf0 ? 4u : 0u) | (ws0[it*4+3] <= tauf0 ? 8u : 0u);
        uint32_t nib1 = (ws1[it*4+0] <= tauf1 ? 1u : 0u) | (ws1[it*4+1] <= tauf1 ? 2u : 0u)
                      | (ws1[it*4+2] <= tauf1 ? 4u : 0u) | (ws1[it*4+3] <= tauf1 ? 8u : 0u);
        PUSHN(nib0, qw0, scnt0)
        PUSHN(nib1, qw1, scnt1)
    }
    MAYBE_DRAIN(0, DRAIN_THR)
    MAYBE_DRAIN(1, DRAIN_THR)

    // ---- main scan: sites 4..35, 1-site prefetch, shared-rsq FMA filter ----
    int vp = wq4 + 4 * 64 + lane;
    float4 n0 = p0g[vp], n1 = p0g[vp + 9216], n2 = p0g[vp + 18432];

    #pragma unroll 1
    for (int it = 4; it < 36; ++it) {
        float4 a0 = n0, a1 = n1, a2 = n2;
        int itn = (it < 35) ? it + 1 : 35;
        int vn = wq4 + itn * 64 + lane;
        n0 = p0g[vn]; n1 = p0g[vn + 9216]; n2 = p0g[vn + 18432];

        uint32_t v = (uint32_t)(wq4 + it * 64 + lane);
        uint32_t nib0 = 0, nib1 = 0;
        #define FILT(comp, bitv)                                                           \
        {                                                                                  \
            float rsf = fmaf(a2.comp, a2.comp, fmaf(a1.comp, a1.comp, a0.comp*a0.comp));   \
            float rh  = rsf * 0.5f;                                                        \
            float cr0 = fmaf(a2.comp, pq0.z, fmaf(a1.comp, pq0.y, a0.comp*pq0.x));         \
            float cr1 = fmaf(a2.comp, pq1.z, fmaf(a1.comp, pq1.y, a0.comp*pq1.x));         \
            if (cr0 >= rh + h0) nib0 |= bitv;                                              \
            if (cr1 >= rh + h1) nib1 |= bitv;                                              \
        }
        FILT(x, 1u) FILT(y, 2u) FILT(z, 4u) FILT(w, 8u)
        #undef FILT

        if (__ballot(nib0 | nib1)) {
            PUSHN(nib0, qw0, scnt0)
            PUSHN(nib1, qw1, scnt1)
            MAYBE_DRAIN(0, DRAIN_THR)
            MAYBE_DRAIN(1, DRAIN_THR)
        }
    }
    // final drains (first-refine guaranteed: warm pushed >= 16 entries)
    MAYBE_DRAIN(0, 1u)
    MAYBE_DRAIN(1, 1u)
    #undef MAYBE_DRAIN
    #undef PUSHN

    // ---- per-wave top-16 for each query -> mbuf ----
    int M0 = stage_compact(kept0, tk0, cbufs[wid], lane);
    select16(kept0, M0, cbufs[wid], &mbuf[0][wid * KK], lane);
    int M1 = stage_compact(kept1, tk1, cbufs[wid], lane);
    select16(kept1, M1, cbufs[wid], &mbuf[1][wid * KK], lane);
    __syncthreads();

    // ---- waves 0,1: merge 64 candidates for q0,q1; emit loss term for row ql+1 ----
    if (wid < 2) {
        int q = wid;
        int ql = qp * 2 + q;
        u64 v = mbuf[q][lane];              // 64 distinct keys
        int rank = 0;
        #pragma unroll 1
        for (int m = 0; m < 64; ++m) {
            uint32_t lo = __shfl((uint32_t)v, m, 64);
            uint32_t hi = __shfl((uint32_t)(v >> 32), m, 64);
            u64 o = ((u64)hi << 32) | lo;
            rank += (o < v) ? 1 : 0;
        }
        int row = ql + 1;
        int slot = b * 256 + ql;
        if (row <= 255) {
            float px1 = pred[(size_t)(b * 256 + row) * 8 + 0];
            float py1 = pred[(size_t)(b * 256 + row) * 8 + 1];
            float tx = 0.0f, ty = 0.0f;
            u64 dkey = ~0ull;
            if (rank < KK) {
                uint32_t idx = (uint32_t)v;
                tx = (float)(idx % WW) / 192.0f;
                ty = (float)(idx / WW) / 192.0f;
                float dx = __fsub_rn(px1, tx);
                float dy = __fsub_rn(py1, ty);
                float d = __fadd_rn(__fmul_rn(dx, dx), __fmul_rn(dy, dy));
                dkey = ((u64)__float_as_uint(d) << 32) | (uint32_t)rank;  // argmin tie -> low rank
            }
            u64 wmin = wave_min_u64(dkey);
            if (dkey == wmin && rank < KK) {
                float ex = __fsub_rn(px1, tx);
                float ey = __fsub_rn(py1, ty);
                partial[slot] = __fadd_rn(__fmul_rn(ex, ex), __fmul_rn(ey, ey));
            }
        } else {
            if (lane == 0) partial[slot] = 0.0f;   // row 0 excluded from loss
        }
    }
}

// ---------- kernel 2: reduce 2048 partials -> mean ----------
__global__ __launch_bounds__(256) void reduce_kernel(const float* __restrict__ partial,
                                                     float* __restrict__ out) {
    __shared__ double sred[256];
    double a = 0.0;
    #pragma unroll
    for (int i = 0; i < 8; ++i) a += (double)partial[i * 256 + threadIdx.x];
    sred[threadIdx.x] = a;
    __syncthreads();
    for (int s = 128; s > 0; s >>= 1) {
        if (threadIdx.x < s) sred[threadIdx.x] += sred[threadIdx.x + s];
        __syncthreads();
    }
    if (threadIdx.x == 0) out[0] = (float)(sred[0] / 2040.0);
}

// ---------- launch ----------
extern "C" void kernel_launch(void* const* d_in, const int* in_sizes, int n_in,
                              void* d_out, int out_size, void* d_ws, size_t ws_size,
                              hipStream_t stream) {
    const float* pred = (const float*)d_in[0];   // (8,256,8) f32
    const float* ref  = (const float*)d_in[1];   // (8,3,192,192) f32
    float* out = (float*)d_out;

    float* partial = (float*)d_ws;               // 2048 floats, fully written each call

    topk_kernel  <<<1024, 256, 0, stream>>>(pred, ref, partial);
    reduce_kernel<<<1, 256, 0, stream>>>(partial, out);
}